// Round 10
// baseline (142.980 us; speedup 1.0000x reference)
//
#include <hip/hip_runtime.h>

// Batched GEMM: C[b][i][j] = sum_d A[b][i][d] * B[b][j][d]
// B=16, M=N=1024, K=256, fp32 in/out, bf16 MFMA compute.
// R10 (=R9 resubmit, VGPR fix): barrier-free direct-from-global structure,
//     register pipeline PINNED via inline-asm global_load_dwordx4 + counted
//     s_waitcnt vmcnt(16) (R7 failed because hipcc sank loads to uses:
//     VGPR=68). Single base/matrix-frag (13-bit signed imm covers kt*128 up
//     to 912B) keeps peak live regs ~250 < 256 cap. No LDS, no barriers.

typedef __attribute__((ext_vector_type(8))) short bf16x8;
typedef __attribute__((ext_vector_type(4))) float f32x4;
typedef __attribute__((ext_vector_type(4))) unsigned int u32x4;

#define NBATCH 16
#define MDIM 1024
#define NDIM 1024
#define KDIM 256

// round-half-up fp32->bf16 pair pack: lo16 = bf(f0), hi16 = bf(f1)
__device__ __forceinline__ unsigned pack_bf2(float f0, float f1) {
  unsigned u0 = __builtin_bit_cast(unsigned, f0) + 0x8000u;
  unsigned u1 = __builtin_bit_cast(unsigned, f1) + 0x8000u;
  return __builtin_amdgcn_perm(u1, u0, 0x07060302u);
}

// asm-pinned 16B load: cannot be sunk/duplicated by the scheduler.
#define GLOAD(dst, addr, IMM)                                    \
  asm volatile("global_load_dwordx4 %0, %1, off offset:%c2"      \
               : "=v"(dst)                                       \
               : "v"(addr), "i"(IMM))

// counted vmem wait + scheduling fence (rule #18: MFMA/VALU get hoisted
// past inline-asm waitcnt unless fenced).
#define WAITV(N)                                                 \
  do {                                                           \
    asm volatile("s_waitcnt vmcnt(" #N ")" ::: "memory");        \
    __builtin_amdgcn_sched_barrier(0);                           \
  } while (0)

__global__ __launch_bounds__(256, 2) void batched_gemm_bt(
    const float* __restrict__ A, const float* __restrict__ B,
    float* __restrict__ C) {
  // XCD chunk swizzle: each XCD works a contiguous 128-block chunk
  // (= 2 batches -> input working set ~= its L2). Verified: FETCH 17MB.
  const int bid = blockIdx.x;
  const int nb  = ((bid & 7) << 7) | (bid >> 3);
  const int batch = nb >> 6;  // 64 tiles (8x8) per batch
  const int tile  = nb & 63;
  const int tm = tile >> 3, tn = tile & 7;

  const int tid  = threadIdx.x;
  const int lane = tid & 63;
  const int wid  = tid >> 6;
  const int wr = wid >> 1, wc = wid & 1;  // wave 2x2 grid, each 64x64 out

  const int lrow = lane & 15;  // fragment row
  const int hi   = lane >> 4;  // k-subslice: floats [hi*8, hi*8+8)

  // Per-lane fragment base addresses (frag m adds m*16 rows). K-step kt is a
  // +kt*128B immediate (max 896+16 = 912 < 4096). Layout verified R7.
  const float* a0 = A + ((size_t)batch * MDIM + tm * 128 + wr * 64 + lrow) * KDIM + hi * 8;
  const float* b0 = B + ((size_t)batch * NDIM + tn * 128 + wc * 64 + lrow) * KDIM + hi * 8;
  unsigned long long baA[4], baB[4];
#pragma unroll
  for (int m = 0; m < 4; ++m) {
    baA[m] = (unsigned long long)(a0 + (size_t)m * 16 * KDIM);
    baB[m] = (unsigned long long)(b0 + (size_t)m * 16 * KDIM);
  }

  // two explicit staging sets (ping-pong), pinned live by asm outputs
  f32x4 sa0[4][2], sb0[4][2], sa1[4][2], sb1[4][2];
  f32x4 acc[4][4];
#pragma unroll
  for (int m = 0; m < 4; ++m)
#pragma unroll
    for (int n = 0; n < 4; ++n)
      acc[m][n] = (f32x4){0.f, 0.f, 0.f, 0.f};

#define ISSUE(sa, sb, IMM)                                       \
  do {                                                           \
    _Pragma("unroll") for (int m = 0; m < 4; ++m) {              \
      GLOAD(sa[m][0], baA[m], (IMM));                            \
      GLOAD(sa[m][1], baA[m], (IMM) + 16);                       \
      GLOAD(sb[m][0], baB[m], (IMM));                            \
      GLOAD(sb[m][1], baB[m], (IMM) + 16);                       \
    }                                                            \
  } while (0)

#define CVT_MFMA(sa, sb)                                         \
  do {                                                           \
    u32x4 af[4], bfv[4];                                         \
    _Pragma("unroll") for (int m = 0; m < 4; ++m) {              \
      af[m][0]  = pack_bf2(sa[m][0][0], sa[m][0][1]);            \
      af[m][1]  = pack_bf2(sa[m][0][2], sa[m][0][3]);            \
      af[m][2]  = pack_bf2(sa[m][1][0], sa[m][1][1]);            \
      af[m][3]  = pack_bf2(sa[m][1][2], sa[m][1][3]);            \
      bfv[m][0] = pack_bf2(sb[m][0][0], sb[m][0][1]);            \
      bfv[m][1] = pack_bf2(sb[m][0][2], sb[m][0][3]);            \
      bfv[m][2] = pack_bf2(sb[m][1][0], sb[m][1][1]);            \
      bfv[m][3] = pack_bf2(sb[m][1][2], sb[m][1][3]);            \
    }                                                            \
    _Pragma("unroll") for (int m = 0; m < 4; ++m)                \
      _Pragma("unroll") for (int n = 0; n < 4; ++n)              \
        acc[m][n] = __builtin_amdgcn_mfma_f32_16x16x32_bf16(     \
            __builtin_bit_cast(bf16x8, af[m]),                   \
            __builtin_bit_cast(bf16x8, bfv[n]), acc[m][n],       \
            0, 0, 0);                                            \
  } while (0)

  // K = 256 -> 8 steps of 32 floats (=128B). Depth-1 pipeline:
  // issue(k+1) -> vmcnt(16) [drains only set k, leaves k+1 in flight]
  // -> convert+MFMA(k). No barriers; waves independent.
  ISSUE(sa0, sb0, 0);    // kt=0

  ISSUE(sa1, sb1, 128);  // kt=1
  WAITV(16);
  CVT_MFMA(sa0, sb0);    // kt=0

  ISSUE(sa0, sb0, 256);  // kt=2
  WAITV(16);
  CVT_MFMA(sa1, sb1);    // kt=1

  ISSUE(sa1, sb1, 384);  // kt=3
  WAITV(16);
  CVT_MFMA(sa0, sb0);    // kt=2

  ISSUE(sa0, sb0, 512);  // kt=4
  WAITV(16);
  CVT_MFMA(sa1, sb1);    // kt=3

  ISSUE(sa1, sb1, 640);  // kt=5
  WAITV(16);
  CVT_MFMA(sa0, sb0);    // kt=4

  ISSUE(sa0, sb0, 768);  // kt=6
  WAITV(16);
  CVT_MFMA(sa1, sb1);    // kt=5

  ISSUE(sa1, sb1, 896);  // kt=7
  WAITV(16);
  CVT_MFMA(sa0, sb0);    // kt=6

  WAITV(0);
  CVT_MFMA(sa1, sb1);    // kt=7

#undef ISSUE
#undef CVT_MFMA

  // C/D layout: col = lane&15, row = (lane>>4)*4 + reg (m89-verified).
  // NT stores: C never re-read -> keep input panels in L2/L3.
  float* Cb = C + (size_t)batch * MDIM * NDIM + (size_t)(tm * 128) * NDIM + tn * 128;
  float* cw = Cb + (size_t)(wr * 64 + hi * 4) * NDIM + wc * 64 + lrow;
#pragma unroll
  for (int m = 0; m < 4; ++m)
#pragma unroll
    for (int n = 0; n < 4; ++n)
#pragma unroll
      for (int j = 0; j < 4; ++j)
        __builtin_nontemporal_store(acc[m][n][j],
                                    &cw[(size_t)(m * 16 + j) * NDIM + n * 16]);
}

extern "C" void kernel_launch(void* const* d_in, const int* in_sizes, int n_in,
                              void* d_out, int out_size, void* d_ws, size_t ws_size,
                              hipStream_t stream) {
  const float* A = (const float*)d_in[0];
  const float* B = (const float*)d_in[1];
  float* C = (float*)d_out;
  batched_gemm_bt<<<dim3(NBATCH * 8 * 8), dim3(256), 0, stream>>>(A, B, C);
}